// Round 5
// baseline (49.051 us; speedup 1.0000x reference)
//
#include <hip/hip_runtime.h>
#include <math.h>

#define N1 8192
#define N2 4096
#define N3 2048

typedef float f4 __attribute__((ext_vector_type(4)));

// ---------- Kernel A: fused l1-recompute + w12/w32 matvec -> l2 ----------
// Each block (4 rows of w12/w32):
//   1. dot 4 w32 rows with l3_state (no l1 dependency; loads issue early)
//   2. recompute l1 = 0.95*l1s + 0.05*tanh(smi) into LDS (VALU, hides w32 loads)
//   3. dot 4 w12 rows with LDS l1
//   4. l2[r] = 0.98*l2s[r] + 0.02*tanh(w12dot + 0.3*w32dot)
// Blocks 0..31 additionally publish l1 to d_out (bitwise-identical recompute).
__global__ __launch_bounds__(256) void k_l12(const float* __restrict__ smi,
                                             const float* __restrict__ l1s,
                                             const float* __restrict__ w12,
                                             const float* __restrict__ w32,
                                             const float* __restrict__ l3s,
                                             const float* __restrict__ l2s,
                                             float* __restrict__ l1_out,
                                             float* __restrict__ l2_out) {
    __shared__ float lds_l1[N1];  // 32 KB -> 4 blocks/CU within 160 KB LDS
    __shared__ float ws[4][4];
    const int t = threadIdx.x;
    const int r0 = blockIdx.x * 4;

    // ---- w32 rows (independent of l1) ----
    const f4* __restrict__ v0 = reinterpret_cast<const f4*>(w32) + (size_t)r0 * (N3 / 4);
    const f4* __restrict__ v1 = v0 + (N3 / 4);
    const f4* __restrict__ v2 = v1 + (N3 / 4);
    const f4* __restrict__ v3 = v2 + (N3 / 4);
    const f4* __restrict__ x3 = reinterpret_cast<const f4*>(l3s);
    float b0 = 0.f, b1 = 0.f, b2 = 0.f, b3 = 0.f;
#pragma unroll
    for (int k = 0; k < (N3 / 4) / 256; ++k) {  // 2 iters
        const int i = t + k * 256;
        f4 xv = x3[i];
        f4 u0 = __builtin_nontemporal_load(&v0[i]);
        f4 u1 = __builtin_nontemporal_load(&v1[i]);
        f4 u2 = __builtin_nontemporal_load(&v2[i]);
        f4 u3 = __builtin_nontemporal_load(&v3[i]);
        b0 = fmaf(u0.x, xv.x, fmaf(u0.y, xv.y, fmaf(u0.z, xv.z, fmaf(u0.w, xv.w, b0))));
        b1 = fmaf(u1.x, xv.x, fmaf(u1.y, xv.y, fmaf(u1.z, xv.z, fmaf(u1.w, xv.w, b1))));
        b2 = fmaf(u2.x, xv.x, fmaf(u2.y, xv.y, fmaf(u2.z, xv.z, fmaf(u2.w, xv.w, b2))));
        b3 = fmaf(u3.x, xv.x, fmaf(u3.y, xv.y, fmaf(u3.z, xv.z, fmaf(u3.w, xv.w, b3))));
    }

    // ---- recompute l1 into LDS (VALU work overlaps the w32 loads above) ----
    {
        const f4* __restrict__ s4 = reinterpret_cast<const f4*>(smi);
        const f4* __restrict__ p4 = reinterpret_cast<const f4*>(l1s);
        f4* __restrict__ d4 = reinterpret_cast<f4*>(lds_l1);
#pragma unroll
        for (int k = 0; k < (N1 / 4) / 256; ++k) {  // 8 iters
            const int i = t + k * 256;
            f4 s = s4[i];
            f4 p = p4[i];
            f4 r;
            r.x = fmaf(0.95f, p.x, 0.05f * tanhf(s.x));
            r.y = fmaf(0.95f, p.y, 0.05f * tanhf(s.y));
            r.z = fmaf(0.95f, p.z, 0.05f * tanhf(s.z));
            r.w = fmaf(0.95f, p.w, 0.05f * tanhf(s.w));
            d4[i] = r;
        }
    }
    __syncthreads();

    // ---- publish l1 (blocks 0..31), issues early and retires under streaming ----
    if (blockIdx.x < 32) {
        const int i = blockIdx.x * 256 + t;
        l1_out[i] = lds_l1[i];
    }

    // ---- w12 rows against LDS l1 ----
    const f4* __restrict__ w0 = reinterpret_cast<const f4*>(w12) + (size_t)r0 * (N1 / 4);
    const f4* __restrict__ w1 = w0 + (N1 / 4);
    const f4* __restrict__ w2 = w1 + (N1 / 4);
    const f4* __restrict__ w3 = w2 + (N1 / 4);
    const f4* __restrict__ x1 = reinterpret_cast<const f4*>(lds_l1);
    float a0 = 0.f, a1 = 0.f, a2 = 0.f, a3 = 0.f;
#pragma unroll
    for (int k = 0; k < (N1 / 4) / 256; ++k) {  // 8 iters
        const int i = t + k * 256;
        f4 xv = x1[i];
        f4 u0 = __builtin_nontemporal_load(&w0[i]);
        f4 u1 = __builtin_nontemporal_load(&w1[i]);
        f4 u2 = __builtin_nontemporal_load(&w2[i]);
        f4 u3 = __builtin_nontemporal_load(&w3[i]);
        a0 = fmaf(u0.x, xv.x, fmaf(u0.y, xv.y, fmaf(u0.z, xv.z, fmaf(u0.w, xv.w, a0))));
        a1 = fmaf(u1.x, xv.x, fmaf(u1.y, xv.y, fmaf(u1.z, xv.z, fmaf(u1.w, xv.w, a1))));
        a2 = fmaf(u2.x, xv.x, fmaf(u2.y, xv.y, fmaf(u2.z, xv.z, fmaf(u2.w, xv.w, a2))));
        a3 = fmaf(u3.x, xv.x, fmaf(u3.y, xv.y, fmaf(u3.z, xv.z, fmaf(u3.w, xv.w, a3))));
    }

    // ---- fold (a + 0.3*b) per-lane, reduce 4 values ----
    float c0 = fmaf(0.3f, b0, a0);
    float c1 = fmaf(0.3f, b1, a1);
    float c2 = fmaf(0.3f, b2, a2);
    float c3 = fmaf(0.3f, b3, a3);
#pragma unroll
    for (int off = 32; off; off >>= 1) {
        c0 += __shfl_down(c0, off, 64);
        c1 += __shfl_down(c1, off, 64);
        c2 += __shfl_down(c2, off, 64);
        c3 += __shfl_down(c3, off, 64);
    }
    if ((t & 63) == 0) {
        const int w = t >> 6;
        ws[w][0] = c0; ws[w][1] = c1; ws[w][2] = c2; ws[w][3] = c3;
    }
    __syncthreads();
    if (t < 4) {
        const int r = r0 + t;
        float tot = ws[0][t] + ws[1][t] + ws[2][t] + ws[3][t];
        l2_out[r] = 0.98f * l2s[r] + 0.02f * tanhf(tot);
    }
}

// ---------- Kernel B: TWO rows of w23 per block ----------
// l3[r] = 0.99*l3_state[r] + 0.01*tanh( w23[r,:]@l2 )
__global__ __launch_bounds__(256) void k_l3(const float* __restrict__ w23,
                                            const float* __restrict__ l2,
                                            const float* __restrict__ l3s,
                                            float* __restrict__ l3) {
    __shared__ float ws[4][2];
    const int r0 = blockIdx.x * 2;
    const int t = threadIdx.x;
    const f4* __restrict__ w0 = reinterpret_cast<const f4*>(w23) + (size_t)r0 * (N2 / 4);
    const f4* __restrict__ w1 = w0 + (N2 / 4);
    const f4* __restrict__ x2 = reinterpret_cast<const f4*>(l2);

    float a0 = 0.f, a1 = 0.f;
#pragma unroll
    for (int k = 0; k < (N2 / 4) / 256; ++k) {  // 4 iters
        const int i = t + k * 256;
        f4 xv = x2[i];
        f4 u0 = __builtin_nontemporal_load(&w0[i]);
        f4 u1 = __builtin_nontemporal_load(&w1[i]);
        a0 = fmaf(u0.x, xv.x, fmaf(u0.y, xv.y, fmaf(u0.z, xv.z, fmaf(u0.w, xv.w, a0))));
        a1 = fmaf(u1.x, xv.x, fmaf(u1.y, xv.y, fmaf(u1.z, xv.z, fmaf(u1.w, xv.w, a1))));
    }
#pragma unroll
    for (int off = 32; off; off >>= 1) {
        a0 += __shfl_down(a0, off, 64);
        a1 += __shfl_down(a1, off, 64);
    }
    if ((t & 63) == 0) { ws[t >> 6][0] = a0; ws[t >> 6][1] = a1; }
    __syncthreads();
    if (t < 2) {
        const int r = r0 + t;
        float tot = ws[0][t] + ws[1][t] + ws[2][t] + ws[3][t];
        l3[r] = 0.99f * l3s[r] + 0.01f * tanhf(tot);
    }
}

// ---------- Kernel C: all scalar reductions, single block, 2 barriers ----------
__global__ __launch_bounds__(1024) void k_fin(const float* __restrict__ out,
                                              const float* __restrict__ corr_in,
                                              const float* __restrict__ coh_in,
                                              float* __restrict__ scal) {
    __shared__ double sred[16][13];
    __shared__ double fin[13];
    const int t = threadIdx.x;
    const f4* __restrict__ o4 = reinterpret_cast<const f4*>(out);
    // f4 offsets: l1 @ 0 (2048), l2 @ 2048 (1024), l3 @ 3072 (512)

    double p[13];
#pragma unroll
    for (int j = 0; j < 13; ++j) p[j] = 0.0;

    for (int i = t; i < 3584; i += 1024) {  // all 14336 elems
        f4 v = o4[i];
#pragma unroll
        for (int c = 0; c < 4; ++c) {
            double d = (double)v[c];
            p[0] += fabs(d); p[1] += d; p[2] += d * d;
        }
    }
    {  // (l1[:4096], l2)
        f4 x = o4[t];
        f4 y = o4[2048 + t];
#pragma unroll
        for (int c = 0; c < 4; ++c) {
            double dx = (double)x[c], dy = (double)y[c];
            p[3] += dx; p[4] += dy; p[5] += dx * dx; p[6] += dy * dy; p[7] += dx * dy;
        }
    }
    if (t < 512) {  // (l2[:2048], l3)
        f4 x = o4[2048 + t];
        f4 y = o4[3072 + t];
#pragma unroll
        for (int c = 0; c < 4; ++c) {
            double dx = (double)x[c], dy = (double)y[c];
            p[8] += dx; p[9] += dy; p[10] += dx * dx; p[11] += dy * dy; p[12] += dx * dy;
        }
    }

#pragma unroll
    for (int j = 0; j < 13; ++j) {
        double v = p[j];
#pragma unroll
        for (int off = 32; off; off >>= 1) v += __shfl_down(v, off, 64);
        p[j] = v;
    }
    if ((t & 63) == 0) {
        const int w = t >> 6;
#pragma unroll
        for (int j = 0; j < 13; ++j) sred[w][j] = p[j];
    }
    __syncthreads();
    if (t < 13) {
        double s = 0.0;
#pragma unroll
        for (int w = 0; w < 16; ++w) s += sred[w][t];
        fin[t] = s;
    }
    __syncthreads();

    if (t == 0) {
        const double n12 = (double)N2;
        const double n23 = (double)N3;
        const double nall = (double)(N1 + N2 + N3);

        double sxy12 = fin[7] - fin[3] * fin[4] / n12;
        double sxx12 = fin[5] - fin[3] * fin[3] / n12;
        double syy12 = fin[6] - fin[4] * fin[4] / n12;
        double den12 = sqrt(sxx12 * syy12);
        double c12 = (den12 > 0.0 && isfinite(den12)) ? sxy12 / den12 : 0.0;

        double sxy23 = fin[12] - fin[8] * fin[9] / n23;
        double sxx23 = fin[10] - fin[8] * fin[8] / n23;
        double syy23 = fin[11] - fin[9] * fin[9] / n23;
        double den23 = sqrt(sxx23 * syy23);
        double c23 = (den23 > 0.0 && isfinite(den23)) ? sxy23 / den23 : 0.0;

        double corr_new = 0.9 * (double)corr_in[0] + 0.1 * (c12 + c23) * 0.5;

        double total = fin[0];
        double var = (fin[2] - fin[1] * fin[1] / nall) / (nall - 1.0);
        double coh = total / (var + 1e-6);
        coh = fmin(fmax(coh, 0.0), 10.0);
        double coh_new = 0.9 * (double)coh_in[0] + 0.1 * coh;

        scal[0] = (float)corr_new;
        scal[1] = (float)coh_new;
        scal[2] = (float)(total / nall);
    }
}

extern "C" void kernel_launch(void* const* d_in, const int* in_sizes, int n_in,
                              void* d_out, int out_size, void* d_ws, size_t ws_size,
                              hipStream_t stream) {
    const float* smi     = (const float*)d_in[0];
    const float* l1s     = (const float*)d_in[1];
    const float* l2s     = (const float*)d_in[2];
    const float* l3s     = (const float*)d_in[3];
    const float* w12     = (const float*)d_in[4];
    const float* w23     = (const float*)d_in[5];
    const float* w32     = (const float*)d_in[6];
    // d_in[7] = w21 is UNUSED by the reference — never read (saves 134 MB).
    const float* corr_in = (const float*)d_in[8];
    const float* coh_in  = (const float*)d_in[9];

    float* out = (float*)d_out;
    float* l1 = out;
    float* l2 = out + N1;
    float* l3 = out + N1 + N2;
    float* scal = out + N1 + N2 + N3;

    k_l12<<<dim3(N2 / 4), dim3(256), 0, stream>>>(smi, l1s, w12, w32, l3s, l2s, l1, l2);
    k_l3<<<dim3(N3 / 2), dim3(256), 0, stream>>>(w23, l2, l3s, l3);
    k_fin<<<dim3(1), dim3(1024), 0, stream>>>(out, corr_in, coh_in, scal);
}